// Round 12
// baseline (863.983 us; speedup 1.0000x reference)
//
#include <hip/hip_runtime.h>
#include <hip/hip_bf16.h>

#define HH 128   // hidden
#define EDD 64   // edge_dim
#define NLAYER 3
#define LN_EPS 1e-5f
#define LROW 136 // LDS row stride in ushorts (272 B: 16B-aligned, bank-safe)

typedef __attribute__((ext_vector_type(8))) __bf16 bf16x8;
typedef __attribute__((ext_vector_type(4))) float f32x4;

static __device__ __forceinline__ float bf2f(unsigned short u) {
    return __uint_as_float(((unsigned)u) << 16);
}
static __device__ __forceinline__ unsigned short f2bf(float f) {
    return __builtin_bit_cast(unsigned short, (__bf16)f);
}
static __device__ __forceinline__ float silu(float x) {
    return x / (1.f + __expf(-x));
}

// ---------------------------------------------------------------------------
// CSR build (once per call; edge_index is layer-invariant)
// ---------------------------------------------------------------------------
__global__ __launch_bounds__(256) void hist_kernel(
    const int* __restrict__ dst, int* __restrict__ cnt, int E)
{
    for (int e = blockIdx.x * blockDim.x + threadIdx.x; e < E;
         e += gridDim.x * blockDim.x)
        atomicAdd(&cnt[dst[e]], 1);
}

__global__ __launch_bounds__(1024) void scan_kernel(
    const int* __restrict__ cnt, int* __restrict__ off, int N)
{
    __shared__ int ls[1024];
    const int t = threadIdx.x;
    const int C = (N + 1023) >> 10;
    const int lo = t * C;
    const int hi = min(lo + C, N);
    int sum = 0;
    for (int i = lo; i < hi; ++i) sum += cnt[i];
    ls[t] = sum;
    __syncthreads();
    for (int d = 1; d < 1024; d <<= 1) {
        int v = (t >= d) ? ls[t - d] : 0;
        __syncthreads();
        ls[t] += v;
        __syncthreads();
    }
    int excl = (t == 0) ? 0 : ls[t - 1];
    for (int i = lo; i < hi; ++i) { off[i] = excl; excl += cnt[i]; }
    if (t == 1023) off[N] = ls[1023];
}

__global__ __launch_bounds__(256) void scatter2_kernel(
    const int* __restrict__ src, const int* __restrict__ dst,
    int* __restrict__ cursor, int* __restrict__ src_s,
    int* __restrict__ eid_s, int E)
{
    if (blockIdx.x == 0 && threadIdx.x < 32) {   // pad tails (32-edge chunks)
        src_s[E + threadIdx.x] = 0;
        eid_s[E + threadIdx.x] = 0;
    }
    for (int e = blockIdx.x * blockDim.x + threadIdx.x; e < E;
         e += gridDim.x * blockDim.x) {
        const int pos = atomicAdd(&cursor[dst[e]], 1);
        src_s[pos] = src[e];
        eid_s[pos] = e;
    }
}

// ---------------------------------------------------------------------------
// Streaming f32 -> bf16 converts (coalesced both sides)
// ---------------------------------------------------------------------------
__global__ __launch_bounds__(256) void conv_ea(
    const float* __restrict__ ea, unsigned short* __restrict__ ea_b,
    long long total4)
{
    for (long long i = blockIdx.x * 256LL + threadIdx.x; i < total4;
         i += gridDim.x * 256LL) {
        const float4 v = reinterpret_cast<const float4*>(ea)[i];
        ushort4 o;
        o.x = f2bf(v.x); o.y = f2bf(v.y); o.z = f2bf(v.z); o.w = f2bf(v.w);
        reinterpret_cast<ushort4*>(ea_b)[i] = o;
    }
}

__global__ __launch_bounds__(256) void conv_s(
    const float* __restrict__ s0, unsigned int* __restrict__ sbp,
    long long total4)
{
    for (long long i = blockIdx.x * 256LL + threadIdx.x; i < total4;
         i += gridDim.x * 256LL) {
        const float4 v = reinterpret_cast<const float4*>(s0)[i];
        const unsigned a = (unsigned)f2bf(v.x) | ((unsigned)f2bf(v.y) << 16);
        const unsigned b = (unsigned)f2bf(v.z) | ((unsigned)f2bf(v.w) << 16);
        reinterpret_cast<uint2*>(sbp)[i] = make_uint2(a, b);
    }
}

// ---------------------------------------------------------------------------
// We (64x128) -> bf16 B-fragments: frag (kt,ct), lane l holds
// B[k = kt*32 + (l>>4)*8 + j][col = ct*16 + (l&15)], kt<2, ct<8.
// ---------------------------------------------------------------------------
__global__ void prep_we(const float* __restrict__ We, bf16x8* __restrict__ WeB)
{
    const int t = blockIdx.x * blockDim.x + threadIdx.x;
    if (t >= NLAYER * 16 * 64) return;
    const int lane  = t & 63;
    const int frag  = (t >> 6) & 15;
    const int layer = t >> 10;
    const int kt = frag >> 3, ct = frag & 7;
    const int col = ct * 16 + (lane & 15);
    const int k0  = kt * 32 + (lane >> 4) * 8;
    bf16x8 v;
    #pragma unroll
    for (int j = 0; j < 8; ++j)
        v[j] = (__bf16)We[(long long)layer * EDD * HH + (k0 + j) * HH + col];
    WeB[t] = v;
}

// ---------------------------------------------------------------------------
// W (128x128) -> bf16 A^T fragments: frag (kt,ct), kt<4, ct<8; lane l holds
// W[k = kt*32 + (l>>4)*8 + j][outcol = ct*16 + (l&15)].
// ---------------------------------------------------------------------------
__global__ void prep_w128(const float* __restrict__ W, bf16x8* __restrict__ WB)
{
    const int t = blockIdx.x * blockDim.x + threadIdx.x;
    if (t >= NLAYER * 32 * 64) return;
    const int lane  = t & 63;
    const int frag  = (t >> 6) & 31;
    const int layer = t >> 11;
    const int kt = frag >> 3, ct = frag & 7;
    const int col = ct * 16 + (lane & 15);
    const int k0  = kt * 32 + (lane >> 4) * 8;
    bf16x8 v;
    #pragma unroll
    for (int j = 0; j < 8; ++j)
        v[j] = (__bf16)W[(long long)layer * HH * HH + (k0 + j) * HH + col];
    WB[t] = v;
}

// ---------------------------------------------------------------------------
// MFMA aggregation: TWO NODES PER BLOCK, 32-EDGE CHUNKS. Waves {0,1}->node0,
// {2,3}->node1 (wave&1 = 64-col half). Per chunk: 256 threads stage 2x32 src
// rows (4x uint4/thread, 4 loads in flight), each wave loads 4 A-fragments
// (2 sixteen-edge halves) and runs 16 MFMA between the same 2 barriers.
// Halves barrier count per edge, doubles memory in flight per phase.
// ---------------------------------------------------------------------------
__global__ __launch_bounds__(256) void gine_agg_mfma(
    const float* __restrict__ s,              // f32 state (self term)
    const unsigned short* __restrict__ sb,    // bf16 shadow of s (gathers)
    const int* __restrict__ src_s,            // dst-sorted src ids, padded
    const int* __restrict__ eid_s,            // dst-sorted edge ids, padded
    const int* __restrict__ off,              // [N+1]
    const unsigned short* __restrict__ ea_b,  // [E][64] bf16, original order
    const bf16x8* __restrict__ WeB,           // this layer's 16 frags
    const float* __restrict__ be,
    unsigned short* __restrict__ hb16,        // out: bf16(s + agg)
    int N, int E)
{
    __shared__ unsigned short lsb[2][32 * LROW];   // 2 nodes x 32 rows

    const int tid  = threadIdx.x;
    const int wave = tid >> 6;
    const int half = wave & 1;    // column half: cols [half*64, half*64+64)
    const int slot = wave >> 1;   // node slot 0/1
    const int lane = tid & 63;
    const int lmod = lane & 15;
    const int ldiv = lane >> 4;

    bf16x8 wb0[4], wb1[4];
    #pragma unroll
    for (int c = 0; c < 4; ++c) {
        wb0[c] = WeB[(0 * 8 + half * 4 + c) * 64 + lane];
        wb1[c] = WeB[(1 * 8 + half * 4 + c) * 64 + lane];
    }
    float bev[4];
    #pragma unroll
    for (int c = 0; c < 4; ++c) bev[c] = be[(half * 4 + c) * 16 + lmod];

    // staging role: 128 threads per node tile; 32 rows x 4 threads x 64B
    const int st_slot = tid >> 7;         // which node's tile
    const int st_row  = (tid >> 2) & 31;  // src row 0..31
    const int st_su   = (tid & 3) * 32;   // starting ushort offset (64B/thread)

    for (int base = blockIdx.x * 2; base < N; base += gridDim.x * 2) {
        const int n0 = base;
        const int n1 = (base + 1 < N) ? base + 1 : base;
        const int q0 = off[n0], q0e = off[n0 + 1];
        const int q1 = off[n1], q1e = off[n1 + 1];
        const int iters = max((q0e - q0 + 31) >> 5, (q1e - q1 + 31) >> 5);

        const int myn = slot ? n1 : n0;
        const int p0  = slot ? q1 : q0;
        const int p1  = slot ? q1e : q0e;
        const int sp0 = st_slot ? q1 : q0;

        float acc[4] = {0.f, 0.f, 0.f, 0.f};

        for (int it = 0; it < iters; ++it) {
            // issue staging gathers early (4 loads in flight per thread)
            const int sidx  = min(sp0 + it * 32 + st_row, E + 31);
            const int snode = src_s[sidx];
            const unsigned short* srow = &sb[(long long)snode * HH + st_su];
            uint4 sv[4];
            #pragma unroll
            for (int j = 0; j < 4; ++j)
                sv[j] = *reinterpret_cast<const uint4*>(srow + j * 8);

            // A fragments for my node's 32 edges (2 sixteen-edge halves)
            const int p   = p0 + it * 32;
            const int rem = p1 - p;
            const int r0 = eid_s[min(p + lmod,      E + 31)];
            const int r1 = eid_s[min(p + 16 + lmod, E + 31)];
            const unsigned short* ar0 = ea_b + (long long)r0 * EDD + ldiv * 8;
            const unsigned short* ar1 = ea_b + (long long)r1 * EDD + ldiv * 8;
            const bf16x8 a0 = *reinterpret_cast<const bf16x8*>(ar0);
            const bf16x8 a1 = *reinterpret_cast<const bf16x8*>(ar0 + 32);
            const bf16x8 a2 = *reinterpret_cast<const bf16x8*>(ar1);
            const bf16x8 a3 = *reinterpret_cast<const bf16x8*>(ar1 + 32);

            __syncthreads();   // previous chunk's readers done with lsb
            unsigned short* drow = &lsb[st_slot][st_row * LROW + st_su];
            #pragma unroll
            for (int j = 0; j < 4; ++j)
                *reinterpret_cast<uint4*>(drow + j * 8) = sv[j];

            // first half: edges p..p+15
            f32x4 cf[4];
            #pragma unroll
            for (int c = 0; c < 4; ++c) {
                f32x4 z = {0.f, 0.f, 0.f, 0.f};
                z = __builtin_amdgcn_mfma_f32_16x16x32_bf16(a0, wb0[c], z, 0, 0, 0);
                z = __builtin_amdgcn_mfma_f32_16x16x32_bf16(a1, wb1[c], z, 0, 0, 0);
                cf[c] = z;
            }

            __syncthreads();   // lsb fully staged

            #pragma unroll
            for (int r = 0; r < 4; ++r) {
                const int row = ldiv * 4 + r;
                if (row < rem) {
                    const unsigned short* lr = &lsb[slot][row * LROW];
                    #pragma unroll
                    for (int c = 0; c < 4; ++c)
                        acc[c] += fmaxf(
                            bf2f(lr[(half * 4 + c) * 16 + lmod]) + cf[c][r] + bev[c],
                            0.f);
                }
            }

            // second half: edges p+16..p+31 (reuses cf registers)
            #pragma unroll
            for (int c = 0; c < 4; ++c) {
                f32x4 z = {0.f, 0.f, 0.f, 0.f};
                z = __builtin_amdgcn_mfma_f32_16x16x32_bf16(a2, wb0[c], z, 0, 0, 0);
                z = __builtin_amdgcn_mfma_f32_16x16x32_bf16(a3, wb1[c], z, 0, 0, 0);
                cf[c] = z;
            }
            #pragma unroll
            for (int r = 0; r < 4; ++r) {
                const int row = 16 + ldiv * 4 + r;
                if (row < rem) {
                    const unsigned short* lr = &lsb[slot][row * LROW];
                    #pragma unroll
                    for (int c = 0; c < 4; ++c)
                        acc[c] += fmaxf(
                            bf2f(lr[(half * 4 + c) * 16 + lmod]) + cf[c][r] + bev[c],
                            0.f);
                }
            }
        }

        #pragma unroll
        for (int c = 0; c < 4; ++c) {
            acc[c] += __shfl_xor(acc[c], 16, 64);
            acc[c] += __shfl_xor(acc[c], 32, 64);
        }
        const float av = (ldiv == 0) ? acc[0] : (ldiv == 1) ? acc[1]
                       : (ldiv == 2) ? acc[2] : acc[3];
        const int col = (half * 4 + ldiv) * 16 + lmod;
        const long long nb = (long long)myn * HH;
        hb16[nb + col] = f2bf(s[nb + col] + av);
    }
}

// ---------------------------------------------------------------------------
// Fused node MLP (both MFMA stages):
//   t1 = silu(h@W1+b1)  -> LDS tile -> v = s + t1@W2 + b2
//   s_out = silu(LN(v)*gamma+beta); also writes bf16 shadow.
// ---------------------------------------------------------------------------
__global__ __launch_bounds__(256) void gine_mlp(
    const float* __restrict__ s_in,
    const unsigned short* __restrict__ h16,  // [N][128] bf16 (from agg)
    const bf16x8* __restrict__ W1B, const float* __restrict__ b1,
    const bf16x8* __restrict__ W2B, const float* __restrict__ b2,
    const float* __restrict__ gamma, const float* __restrict__ beta,
    float* __restrict__ s_out,
    unsigned short* __restrict__ sb_out,     // bf16 shadow
    int N)
{
    __shared__ unsigned short t1t[16 * LROW];   // 16 nodes x 128 cols
    __shared__ float2 red[4][16];

    const int wave = threadIdx.x >> 6;
    const int lane = threadIdx.x & 63;
    const int lmod = lane & 15;
    const int ldiv = lane >> 4;

    bf16x8 wf1[4][2], wf2[4][2];
    #pragma unroll
    for (int kt = 0; kt < 4; ++kt) {
        wf1[kt][0] = W1B[(kt * 8 + 2 * wave    ) * 64 + lane];
        wf1[kt][1] = W1B[(kt * 8 + 2 * wave + 1) * 64 + lane];
        wf2[kt][0] = W2B[(kt * 8 + 2 * wave    ) * 64 + lane];
        wf2[kt][1] = W2B[(kt * 8 + 2 * wave + 1) * 64 + lane];
    }
    float4 b1v[2], b2v[2], gv[2], ev[2];
    #pragma unroll
    for (int ctl = 0; ctl < 2; ++ctl) {
        const int oc0 = (2 * wave + ctl) * 16 + ldiv * 4;
        b1v[ctl] = *reinterpret_cast<const float4*>(&b1[oc0]);
        b2v[ctl] = *reinterpret_cast<const float4*>(&b2[oc0]);
        gv[ctl]  = *reinterpret_cast<const float4*>(&gamma[oc0]);
        ev[ctl]  = *reinterpret_cast<const float4*>(&beta[oc0]);
    }

    const int ntiles = (N + 15) >> 4;
    for (int t = blockIdx.x; t < ntiles; t += gridDim.x) {
        const int node = t * 16 + lmod;
        const long long nb = (long long)min(node, N - 1) * HH;

        // ---- stage 1: t1 = silu(h @ W1 + b1)
        f32x4 c0 = {0.f, 0.f, 0.f, 0.f};
        f32x4 c1 = {0.f, 0.f, 0.f, 0.f};
        #pragma unroll
        for (int kt = 0; kt < 4; ++kt) {
            const bf16x8 hf = *reinterpret_cast<const bf16x8*>(
                &h16[nb + kt * 32 + ldiv * 8]);
            c0 = __builtin_amdgcn_mfma_f32_16x16x32_bf16(wf1[kt][0], hf, c0, 0, 0, 0);
            c1 = __builtin_amdgcn_mfma_f32_16x16x32_bf16(wf1[kt][1], hf, c1, 0, 0, 0);
        }
        #pragma unroll
        for (int ctl = 0; ctl < 2; ++ctl) {
            const f32x4 cc = ctl ? c1 : c0;
            const float4 bb = ctl ? b1v[1] : b1v[0];
            uint2 pk;
            pk.x = (unsigned)f2bf(silu(cc[0] + bb.x)) |
                   ((unsigned)f2bf(silu(cc[1] + bb.y)) << 16);
            pk.y = (unsigned)f2bf(silu(cc[2] + bb.z)) |
                   ((unsigned)f2bf(silu(cc[3] + bb.w)) << 16);
            const int oc0 = (2 * wave + ctl) * 16 + ldiv * 4;
            *reinterpret_cast<uint2*>(&t1t[lmod * LROW + oc0]) = pk;
        }
        __syncthreads();   // t1 tile complete

        // ---- stage 2: v = s + t1 @ W2 + b2
        f32x4 d0 = {0.f, 0.f, 0.f, 0.f};
        f32x4 d1 = {0.f, 0.f, 0.f, 0.f};
        #pragma unroll
        for (int kt = 0; kt < 4; ++kt) {
            const bf16x8 tf = *reinterpret_cast<const bf16x8*>(
                &t1t[lmod * LROW + kt * 32 + ldiv * 8]);
            d0 = __builtin_amdgcn_mfma_f32_16x16x32_bf16(wf2[kt][0], tf, d0, 0, 0, 0);
            d1 = __builtin_amdgcn_mfma_f32_16x16x32_bf16(wf2[kt][1], tf, d1, 0, 0, 0);
        }

        float v[2][4];
        float sum = 0.f, ssq = 0.f;
        #pragma unroll
        for (int ctl = 0; ctl < 2; ++ctl) {
            const int oc0 = (2 * wave + ctl) * 16 + ldiv * 4;
            const float4 sv = *reinterpret_cast<const float4*>(&s_in[nb + oc0]);
            const f32x4 dd = ctl ? d1 : d0;
            const float4 bb = ctl ? b2v[1] : b2v[0];
            v[ctl][0] = sv.x + dd[0] + bb.x;
            v[ctl][1] = sv.y + dd[1] + bb.y;
            v[ctl][2] = sv.z + dd[2] + bb.z;
            v[ctl][3] = sv.w + dd[3] + bb.w;
            #pragma unroll
            for (int r = 0; r < 4; ++r) { sum += v[ctl][r]; ssq += v[ctl][r] * v[ctl][r]; }
        }
        sum += __shfl_xor(sum, 16, 64); sum += __shfl_xor(sum, 32, 64);
        ssq += __shfl_xor(ssq, 16, 64); ssq += __shfl_xor(ssq, 32, 64);
        if (ldiv == 0) red[wave][lmod] = make_float2(sum, ssq);
        __syncthreads();
        float ts = 0.f, tq = 0.f;
        #pragma unroll
        for (int w = 0; w < 4; ++w) {
            const float2 rr = red[w][lmod];
            ts += rr.x; tq += rr.y;
        }
        __syncthreads();   // also guards t1t reuse next iteration

        const float mu = ts * (1.0f / HH);
        const float var = tq * (1.0f / HH) - mu * mu;
        const float rs = rsqrtf(var + LN_EPS);

        if (node < N) {
            #pragma unroll
            for (int ctl = 0; ctl < 2; ++ctl) {
                const int oc0 = (2 * wave + ctl) * 16 + ldiv * 4;
                float o[4];
                o[0] = silu((v[ctl][0] - mu) * rs * gv[ctl].x + ev[ctl].x);
                o[1] = silu((v[ctl][1] - mu) * rs * gv[ctl].y + ev[ctl].y);
                o[2] = silu((v[ctl][2] - mu) * rs * gv[ctl].z + ev[ctl].z);
                o[3] = silu((v[ctl][3] - mu) * rs * gv[ctl].w + ev[ctl].w);
                *reinterpret_cast<float4*>(&s_out[nb + oc0]) =
                    make_float4(o[0], o[1], o[2], o[3]);
                uint2 pk;
                pk.x = (unsigned)f2bf(o[0]) | ((unsigned)f2bf(o[1]) << 16);
                pk.y = (unsigned)f2bf(o[2]) | ((unsigned)f2bf(o[3]) << 16);
                *reinterpret_cast<uint2*>(&sb_out[nb + oc0]) = pk;
            }
        }
    }
}

// ---------------------------------------------------------------------------
extern "C" void kernel_launch(void* const* d_in, const int* in_sizes, int n_in,
                              void* d_out, int out_size, void* d_ws, size_t ws_size,
                              hipStream_t stream) {
    const float* s0  = (const float*)d_in[0];
    const int*   ei  = (const int*)  d_in[1];
    const float* ea  = (const float*)d_in[2];
    const float* We  = (const float*)d_in[3];
    const float* be  = (const float*)d_in[4];
    const float* W1  = (const float*)d_in[5];
    const float* b1  = (const float*)d_in[6];
    const float* W2  = (const float*)d_in[7];
    const float* b2  = (const float*)d_in[8];
    const float* gm  = (const float*)d_in[9];
    const float* bt  = (const float*)d_in[10];

    const int NH = in_sizes[0];          // N * 128
    const int N  = NH / HH;
    const int E  = in_sizes[1] / 2;
    const int* src = ei;
    const int* dst = ei + E;

    // ws layout
    float*          sbuf  = (float*)d_ws;                       // [N*H] f32
    unsigned short* sb    = (unsigned short*)(sbuf + NH);       // [N*H] bf16 shadow
    unsigned short* hb16  = sb + NH;                            // [N*H] bf16 h
    unsigned short* ea_b  = hb16 + NH;                          // [E*64] bf16
    bf16x8*         WeB   = (bf16x8*)(ea_b + (size_t)E * EDD);  // [3*16*64]
    bf16x8*         W1B   = WeB + NLAYER * 16 * 64;             // [3*32*64]
    bf16x8*         W2B   = W1B + NLAYER * 32 * 64;             // [3*32*64]
    int*            src_s = (int*)(W2B + NLAYER * 32 * 64);     // [E+32]
    int*            eid_s = src_s + (E + 32);                   // [E+32]
    int*            off   = eid_s + (E + 32);                   // [N+1]
    int*            cursor= off + (N + 1);                      // [N] (also cnt)

    hipMemcpyAsync(sbuf, s0, sizeof(float) * NH, hipMemcpyDeviceToDevice, stream);

    // ---- one-time preprocessing
    hipMemsetAsync(cursor, 0, sizeof(int) * N, stream);
    hist_kernel<<<1024, 256, 0, stream>>>(dst, cursor, E);
    scan_kernel<<<1, 1024, 0, stream>>>(cursor, off, N);
    hipMemcpyAsync(cursor, off, sizeof(int) * N, hipMemcpyDeviceToDevice, stream);
    scatter2_kernel<<<1024, 256, 0, stream>>>(src, dst, cursor, src_s, eid_s, E);
    conv_ea<<<2048, 256, 0, stream>>>(ea, ea_b, (long long)E * EDD / 4);
    conv_s<<<1024, 256, 0, stream>>>(s0, (unsigned int*)sb, (long long)NH / 4);
    prep_we<<<12, 256, 0, stream>>>(We, WeB);
    prep_w128<<<24, 256, 0, stream>>>(W1, W1B);
    prep_w128<<<24, 256, 0, stream>>>(W2, W2B);

    for (int l = 0; l < NLAYER; ++l) {
        gine_agg_mfma<<<4096, 256, 0, stream>>>(sbuf, sb, src_s, eid_s, off, ea_b,
                                                WeB + (size_t)l * 16 * 64,
                                                be + l * HH, hb16, N, E);
        float* sout = (l == NLAYER - 1) ? (float*)d_out : sbuf;
        gine_mlp<<<2048, 256, 0, stream>>>(sbuf, hb16,
                                           W1B + (size_t)l * 32 * 64, b1 + l * HH,
                                           W2B + (size_t)l * 32 * 64, b2 + l * HH,
                                           gm + l * HH, bt + l * HH,
                                           sout, sb, N);
    }
}

// Round 13
// 611.813 us; speedup vs baseline: 1.4122x; 1.4122x over previous
//
#include <hip/hip_runtime.h>
#include <hip/hip_bf16.h>

#define HH 128   // hidden
#define EDD 64   // edge_dim
#define NLAYER 3
#define LN_EPS 1e-5f
#define LROW 136 // LDS row stride in ushorts (272 B: 16B-aligned, bank-safe)

typedef __attribute__((ext_vector_type(8))) __bf16 bf16x8;
typedef __attribute__((ext_vector_type(4))) float f32x4;

static __device__ __forceinline__ float bf2f(unsigned short u) {
    return __uint_as_float(((unsigned)u) << 16);
}
static __device__ __forceinline__ unsigned short f2bf(float f) {
    return __builtin_bit_cast(unsigned short, (__bf16)f);
}
static __device__ __forceinline__ float silu(float x) {
    return x / (1.f + __expf(-x));
}

// ---------------------------------------------------------------------------
// CSR build (once per call; edge_index is layer-invariant)
// ---------------------------------------------------------------------------
__global__ __launch_bounds__(256) void hist_kernel(
    const int* __restrict__ dst, int* __restrict__ cnt, int E)
{
    for (int e = blockIdx.x * blockDim.x + threadIdx.x; e < E;
         e += gridDim.x * blockDim.x)
        atomicAdd(&cnt[dst[e]], 1);
}

__global__ __launch_bounds__(1024) void scan_kernel(
    const int* __restrict__ cnt, int* __restrict__ off, int N)
{
    __shared__ int ls[1024];
    const int t = threadIdx.x;
    const int C = (N + 1023) >> 10;
    const int lo = t * C;
    const int hi = min(lo + C, N);
    int sum = 0;
    for (int i = lo; i < hi; ++i) sum += cnt[i];
    ls[t] = sum;
    __syncthreads();
    for (int d = 1; d < 1024; d <<= 1) {
        int v = (t >= d) ? ls[t - d] : 0;
        __syncthreads();
        ls[t] += v;
        __syncthreads();
    }
    int excl = (t == 0) ? 0 : ls[t - 1];
    for (int i = lo; i < hi; ++i) { off[i] = excl; excl += cnt[i]; }
    if (t == 1023) off[N] = ls[1023];
}

__global__ __launch_bounds__(256) void scatter2_kernel(
    const int* __restrict__ src, const int* __restrict__ dst,
    int* __restrict__ cursor, int* __restrict__ src_s,
    int* __restrict__ eid_s, int E)
{
    if (blockIdx.x == 0 && threadIdx.x < 16) {   // pad tails
        src_s[E + threadIdx.x] = 0;
        eid_s[E + threadIdx.x] = 0;
    }
    for (int e = blockIdx.x * blockDim.x + threadIdx.x; e < E;
         e += gridDim.x * blockDim.x) {
        const int pos = atomicAdd(&cursor[dst[e]], 1);
        src_s[pos] = src[e];
        eid_s[pos] = e;
    }
}

// ---------------------------------------------------------------------------
// Streaming f32 -> bf16 converts (coalesced both sides)
// ---------------------------------------------------------------------------
__global__ __launch_bounds__(256) void conv_ea(
    const float* __restrict__ ea, unsigned short* __restrict__ ea_b,
    long long total4)
{
    for (long long i = blockIdx.x * 256LL + threadIdx.x; i < total4;
         i += gridDim.x * 256LL) {
        const float4 v = reinterpret_cast<const float4*>(ea)[i];
        ushort4 o;
        o.x = f2bf(v.x); o.y = f2bf(v.y); o.z = f2bf(v.z); o.w = f2bf(v.w);
        reinterpret_cast<ushort4*>(ea_b)[i] = o;
    }
}

__global__ __launch_bounds__(256) void conv_s(
    const float* __restrict__ s0, unsigned int* __restrict__ sbp,
    long long total4)
{
    for (long long i = blockIdx.x * 256LL + threadIdx.x; i < total4;
         i += gridDim.x * 256LL) {
        const float4 v = reinterpret_cast<const float4*>(s0)[i];
        const unsigned a = (unsigned)f2bf(v.x) | ((unsigned)f2bf(v.y) << 16);
        const unsigned b = (unsigned)f2bf(v.z) | ((unsigned)f2bf(v.w) << 16);
        reinterpret_cast<uint2*>(sbp)[i] = make_uint2(a, b);
    }
}

// ---------------------------------------------------------------------------
// We (64x128) -> bf16 B-fragments: frag (kt,ct), lane l holds
// B[k = kt*32 + (l>>4)*8 + j][col = ct*16 + (l&15)], kt<2, ct<8.
// ---------------------------------------------------------------------------
__global__ void prep_we(const float* __restrict__ We, bf16x8* __restrict__ WeB)
{
    const int t = blockIdx.x * blockDim.x + threadIdx.x;
    if (t >= NLAYER * 16 * 64) return;
    const int lane  = t & 63;
    const int frag  = (t >> 6) & 15;
    const int layer = t >> 10;
    const int kt = frag >> 3, ct = frag & 7;
    const int col = ct * 16 + (lane & 15);
    const int k0  = kt * 32 + (lane >> 4) * 8;
    bf16x8 v;
    #pragma unroll
    for (int j = 0; j < 8; ++j)
        v[j] = (__bf16)We[(long long)layer * EDD * HH + (k0 + j) * HH + col];
    WeB[t] = v;
}

// ---------------------------------------------------------------------------
// W (128x128) -> bf16 A^T fragments: frag (kt,ct), kt<4, ct<8; lane l holds
// W[k = kt*32 + (l>>4)*8 + j][outcol = ct*16 + (l&15)].
// ---------------------------------------------------------------------------
__global__ void prep_w128(const float* __restrict__ W, bf16x8* __restrict__ WB)
{
    const int t = blockIdx.x * blockDim.x + threadIdx.x;
    if (t >= NLAYER * 32 * 64) return;
    const int lane  = t & 63;
    const int frag  = (t >> 6) & 31;
    const int layer = t >> 11;
    const int kt = frag >> 3, ct = frag & 7;
    const int col = ct * 16 + (lane & 15);
    const int k0  = kt * 32 + (lane >> 4) * 8;
    bf16x8 v;
    #pragma unroll
    for (int j = 0; j < 8; ++j)
        v[j] = (__bf16)W[(long long)layer * HH * HH + (k0 + j) * HH + col];
    WB[t] = v;
}

// ---------------------------------------------------------------------------
// MFMA aggregation: TWO NODES PER BLOCK, 16-edge chunks (r11's proven 128 us
// structure), now with REGISTER-SIDE 2-DEEP PIPELINE: chunk it+1's staging
// values and A-fragments are prefetched right after chunk it's LDS write, so
// their latency hides under MFMA + LDS-consume. launch_bounds(256,3) raises
// the VGPR cap (~170) so the prefetch does NOT spill (r12 lesson).
// ---------------------------------------------------------------------------
__global__ __launch_bounds__(256, 3) void gine_agg_mfma(
    const float* __restrict__ s,              // f32 state (self term)
    const unsigned short* __restrict__ sb,    // bf16 shadow of s (gathers)
    const int* __restrict__ src_s,            // dst-sorted src ids, padded
    const int* __restrict__ eid_s,            // dst-sorted edge ids, padded
    const int* __restrict__ off,              // [N+1]
    const unsigned short* __restrict__ ea_b,  // [E][64] bf16, original order
    const bf16x8* __restrict__ WeB,           // this layer's 16 frags
    const float* __restrict__ be,
    unsigned short* __restrict__ hb16,        // out: bf16(s + agg)
    int N, int E)
{
    __shared__ unsigned short lsb[2][16 * LROW];   // 2 nodes x 16 rows

    const int tid  = threadIdx.x;
    const int wave = tid >> 6;
    const int half = wave & 1;    // column half: cols [half*64, half*64+64)
    const int slot = wave >> 1;   // node slot 0/1
    const int lane = tid & 63;
    const int lmod = lane & 15;
    const int ldiv = lane >> 4;

    bf16x8 wb0[4], wb1[4];
    #pragma unroll
    for (int c = 0; c < 4; ++c) {
        wb0[c] = WeB[(0 * 8 + half * 4 + c) * 64 + lane];
        wb1[c] = WeB[(1 * 8 + half * 4 + c) * 64 + lane];
    }
    float bev[4];
    #pragma unroll
    for (int c = 0; c < 4; ++c) bev[c] = be[(half * 4 + c) * 16 + lmod];

    // staging role: 128 threads per node tile; 16 rows x 8 threads x 32B
    const int st_slot = tid >> 7;         // which node's tile
    const int st_row  = (tid >> 3) & 15;  // src row 0..15
    const int st_su   = (tid & 7) * 16;   // ushort offset (32B/thread)

    for (int base = blockIdx.x * 2; base < N; base += gridDim.x * 2) {
        const int n0 = base;
        const int n1 = (base + 1 < N) ? base + 1 : base;
        const int q0 = off[n0], q0e = off[n0 + 1];
        const int q1 = off[n1], q1e = off[n1 + 1];
        const int iters = max((q0e - q0 + 15) >> 4, (q1e - q1 + 15) >> 4);

        const int myn = slot ? n1 : n0;
        const int p0  = slot ? q1 : q0;
        const int p1  = slot ? q1e : q0e;
        const int sp0 = st_slot ? q1 : q0;

        float acc[4] = {0.f, 0.f, 0.f, 0.f};

        // ---- prologue: chunk 0 staging values + A-fragments into registers
        int snode = src_s[min(sp0 + st_row, E + 15)];
        const unsigned short* srow0 = &sb[(long long)snode * HH + st_su];
        uint4 sva = *reinterpret_cast<const uint4*>(srow0);
        uint4 svb = *reinterpret_cast<const uint4*>(srow0 + 8);
        int rowid = eid_s[min(p0 + lmod, E + 15)];
        const unsigned short* ar0 = ea_b + (long long)rowid * EDD + ldiv * 8;
        bf16x8 a0 = *reinterpret_cast<const bf16x8*>(ar0);
        bf16x8 a1 = *reinterpret_cast<const bf16x8*>(ar0 + 32);

        for (int it = 0; it < iters; ++it) {
            __syncthreads();   // previous chunk's readers done with lsb
            unsigned short* drow = &lsb[st_slot][st_row * LROW + st_su];
            *reinterpret_cast<uint4*>(drow)     = sva;
            *reinterpret_cast<uint4*>(drow + 8) = svb;

            // ---- prefetch chunk it+1 (latency hides under MFMA + consume)
            uint4 nva = sva, nvb = svb;
            bf16x8 na0 = a0, na1 = a1;
            if (it + 1 < iters) {
                const int ns = src_s[min(sp0 + (it + 1) * 16 + st_row, E + 15)];
                const unsigned short* nsr = &sb[(long long)ns * HH + st_su];
                nva = *reinterpret_cast<const uint4*>(nsr);
                nvb = *reinterpret_cast<const uint4*>(nsr + 8);
                const int nr = eid_s[min(p0 + (it + 1) * 16 + lmod, E + 15)];
                const unsigned short* nar = ea_b + (long long)nr * EDD + ldiv * 8;
                na0 = *reinterpret_cast<const bf16x8*>(nar);
                na1 = *reinterpret_cast<const bf16x8*>(nar + 32);
            }

            // ---- MFMA for current chunk
            f32x4 cf[4];
            #pragma unroll
            for (int c = 0; c < 4; ++c) {
                f32x4 z = {0.f, 0.f, 0.f, 0.f};
                z = __builtin_amdgcn_mfma_f32_16x16x32_bf16(a0, wb0[c], z, 0, 0, 0);
                z = __builtin_amdgcn_mfma_f32_16x16x32_bf16(a1, wb1[c], z, 0, 0, 0);
                cf[c] = z;
            }

            __syncthreads();   // lsb fully staged

            const int rem = p1 - (p0 + it * 16);
            #pragma unroll
            for (int r = 0; r < 4; ++r) {
                if (ldiv * 4 + r < rem) {
                    const unsigned short* lr = &lsb[slot][(ldiv * 4 + r) * LROW];
                    #pragma unroll
                    for (int c = 0; c < 4; ++c)
                        acc[c] += fmaxf(
                            bf2f(lr[(half * 4 + c) * 16 + lmod]) + cf[c][r] + bev[c],
                            0.f);
                }
            }

            sva = nva; svb = nvb; a0 = na0; a1 = na1;
        }

        #pragma unroll
        for (int c = 0; c < 4; ++c) {
            acc[c] += __shfl_xor(acc[c], 16, 64);
            acc[c] += __shfl_xor(acc[c], 32, 64);
        }
        const float av = (ldiv == 0) ? acc[0] : (ldiv == 1) ? acc[1]
                       : (ldiv == 2) ? acc[2] : acc[3];
        const int col = (half * 4 + ldiv) * 16 + lmod;
        const long long nb = (long long)myn * HH;
        hb16[nb + col] = f2bf(s[nb + col] + av);
    }
}

// ---------------------------------------------------------------------------
// Fused node MLP (both MFMA stages):
//   t1 = silu(h@W1+b1)  -> LDS tile -> v = s + t1@W2 + b2
//   s_out = silu(LN(v)*gamma+beta); also writes bf16 shadow.
// ---------------------------------------------------------------------------
__global__ __launch_bounds__(256) void gine_mlp(
    const float* __restrict__ s_in,
    const unsigned short* __restrict__ h16,  // [N][128] bf16 (from agg)
    const bf16x8* __restrict__ W1B, const float* __restrict__ b1,
    const bf16x8* __restrict__ W2B, const float* __restrict__ b2,
    const float* __restrict__ gamma, const float* __restrict__ beta,
    float* __restrict__ s_out,
    unsigned short* __restrict__ sb_out,     // bf16 shadow
    int N)
{
    __shared__ unsigned short t1t[16 * LROW];   // 16 nodes x 128 cols
    __shared__ float2 red[4][16];

    const int wave = threadIdx.x >> 6;
    const int lane = threadIdx.x & 63;
    const int lmod = lane & 15;
    const int ldiv = lane >> 4;

    bf16x8 wf1[4][2], wf2[4][2];
    #pragma unroll
    for (int kt = 0; kt < 4; ++kt) {
        wf1[kt][0] = W1B[(kt * 8 + 2 * wave    ) * 64 + lane];
        wf1[kt][1] = W1B[(kt * 8 + 2 * wave + 1) * 64 + lane];
        wf2[kt][0] = W2B[(kt * 8 + 2 * wave    ) * 64 + lane];
        wf2[kt][1] = W2B[(kt * 8 + 2 * wave + 1) * 64 + lane];
    }
    float4 b1v[2], b2v[2], gv[2], ev[2];
    #pragma unroll
    for (int ctl = 0; ctl < 2; ++ctl) {
        const int oc0 = (2 * wave + ctl) * 16 + ldiv * 4;
        b1v[ctl] = *reinterpret_cast<const float4*>(&b1[oc0]);
        b2v[ctl] = *reinterpret_cast<const float4*>(&b2[oc0]);
        gv[ctl]  = *reinterpret_cast<const float4*>(&gamma[oc0]);
        ev[ctl]  = *reinterpret_cast<const float4*>(&beta[oc0]);
    }

    const int ntiles = (N + 15) >> 4;
    for (int t = blockIdx.x; t < ntiles; t += gridDim.x) {
        const int node = t * 16 + lmod;
        const long long nb = (long long)min(node, N - 1) * HH;

        // ---- stage 1: t1 = silu(h @ W1 + b1)
        f32x4 c0 = {0.f, 0.f, 0.f, 0.f};
        f32x4 c1 = {0.f, 0.f, 0.f, 0.f};
        #pragma unroll
        for (int kt = 0; kt < 4; ++kt) {
            const bf16x8 hf = *reinterpret_cast<const bf16x8*>(
                &h16[nb + kt * 32 + ldiv * 8]);
            c0 = __builtin_amdgcn_mfma_f32_16x16x32_bf16(wf1[kt][0], hf, c0, 0, 0, 0);
            c1 = __builtin_amdgcn_mfma_f32_16x16x32_bf16(wf1[kt][1], hf, c1, 0, 0, 0);
        }
        #pragma unroll
        for (int ctl = 0; ctl < 2; ++ctl) {
            const f32x4 cc = ctl ? c1 : c0;
            const float4 bb = ctl ? b1v[1] : b1v[0];
            uint2 pk;
            pk.x = (unsigned)f2bf(silu(cc[0] + bb.x)) |
                   ((unsigned)f2bf(silu(cc[1] + bb.y)) << 16);
            pk.y = (unsigned)f2bf(silu(cc[2] + bb.z)) |
                   ((unsigned)f2bf(silu(cc[3] + bb.w)) << 16);
            const int oc0 = (2 * wave + ctl) * 16 + ldiv * 4;
            *reinterpret_cast<uint2*>(&t1t[lmod * LROW + oc0]) = pk;
        }
        __syncthreads();   // t1 tile complete

        // ---- stage 2: v = s + t1 @ W2 + b2
        f32x4 d0 = {0.f, 0.f, 0.f, 0.f};
        f32x4 d1 = {0.f, 0.f, 0.f, 0.f};
        #pragma unroll
        for (int kt = 0; kt < 4; ++kt) {
            const bf16x8 tf = *reinterpret_cast<const bf16x8*>(
                &t1t[lmod * LROW + kt * 32 + ldiv * 8]);
            d0 = __builtin_amdgcn_mfma_f32_16x16x32_bf16(wf2[kt][0], tf, d0, 0, 0, 0);
            d1 = __builtin_amdgcn_mfma_f32_16x16x32_bf16(wf2[kt][1], tf, d1, 0, 0, 0);
        }

        float v[2][4];
        float sum = 0.f, ssq = 0.f;
        #pragma unroll
        for (int ctl = 0; ctl < 2; ++ctl) {
            const int oc0 = (2 * wave + ctl) * 16 + ldiv * 4;
            const float4 sv = *reinterpret_cast<const float4*>(&s_in[nb + oc0]);
            const f32x4 dd = ctl ? d1 : d0;
            const float4 bb = ctl ? b2v[1] : b2v[0];
            v[ctl][0] = sv.x + dd[0] + bb.x;
            v[ctl][1] = sv.y + dd[1] + bb.y;
            v[ctl][2] = sv.z + dd[2] + bb.z;
            v[ctl][3] = sv.w + dd[3] + bb.w;
            #pragma unroll
            for (int r = 0; r < 4; ++r) { sum += v[ctl][r]; ssq += v[ctl][r] * v[ctl][r]; }
        }
        sum += __shfl_xor(sum, 16, 64); sum += __shfl_xor(sum, 32, 64);
        ssq += __shfl_xor(ssq, 16, 64); ssq += __shfl_xor(ssq, 32, 64);
        if (ldiv == 0) red[wave][lmod] = make_float2(sum, ssq);
        __syncthreads();
        float ts = 0.f, tq = 0.f;
        #pragma unroll
        for (int w = 0; w < 4; ++w) {
            const float2 rr = red[w][lmod];
            ts += rr.x; tq += rr.y;
        }
        __syncthreads();   // also guards t1t reuse next iteration

        const float mu = ts * (1.0f / HH);
        const float var = tq * (1.0f / HH) - mu * mu;
        const float rs = rsqrtf(var + LN_EPS);

        if (node < N) {
            #pragma unroll
            for (int ctl = 0; ctl < 2; ++ctl) {
                const int oc0 = (2 * wave + ctl) * 16 + ldiv * 4;
                float o[4];
                o[0] = silu((v[ctl][0] - mu) * rs * gv[ctl].x + ev[ctl].x);
                o[1] = silu((v[ctl][1] - mu) * rs * gv[ctl].y + ev[ctl].y);
                o[2] = silu((v[ctl][2] - mu) * rs * gv[ctl].z + ev[ctl].z);
                o[3] = silu((v[ctl][3] - mu) * rs * gv[ctl].w + ev[ctl].w);
                *reinterpret_cast<float4*>(&s_out[nb + oc0]) =
                    make_float4(o[0], o[1], o[2], o[3]);
                uint2 pk;
                pk.x = (unsigned)f2bf(o[0]) | ((unsigned)f2bf(o[1]) << 16);
                pk.y = (unsigned)f2bf(o[2]) | ((unsigned)f2bf(o[3]) << 16);
                *reinterpret_cast<uint2*>(&sb_out[nb + oc0]) = pk;
            }
        }
    }
}

// ---------------------------------------------------------------------------
extern "C" void kernel_launch(void* const* d_in, const int* in_sizes, int n_in,
                              void* d_out, int out_size, void* d_ws, size_t ws_size,
                              hipStream_t stream) {
    const float* s0  = (const float*)d_in[0];
    const int*   ei  = (const int*)  d_in[1];
    const float* ea  = (const float*)d_in[2];
    const float* We  = (const float*)d_in[3];
    const float* be  = (const float*)d_in[4];
    const float* W1  = (const float*)d_in[5];
    const float* b1  = (const float*)d_in[6];
    const float* W2  = (const float*)d_in[7];
    const float* b2  = (const float*)d_in[8];
    const float* gm  = (const float*)d_in[9];
    const float* bt  = (const float*)d_in[10];

    const int NH = in_sizes[0];          // N * 128
    const int N  = NH / HH;
    const int E  = in_sizes[1] / 2;
    const int* src = ei;
    const int* dst = ei + E;

    // ws layout
    float*          sbuf  = (float*)d_ws;                       // [N*H] f32
    unsigned short* sb    = (unsigned short*)(sbuf + NH);       // [N*H] bf16 shadow
    unsigned short* hb16  = sb + NH;                            // [N*H] bf16 h
    unsigned short* ea_b  = hb16 + NH;                          // [E*64] bf16
    bf16x8*         WeB   = (bf16x8*)(ea_b + (size_t)E * EDD);  // [3*16*64]
    bf16x8*         W1B   = WeB + NLAYER * 16 * 64;             // [3*32*64]
    bf16x8*         W2B   = W1B + NLAYER * 32 * 64;             // [3*32*64]
    int*            src_s = (int*)(W2B + NLAYER * 32 * 64);     // [E+16]
    int*            eid_s = src_s + (E + 16);                   // [E+16]
    int*            off   = eid_s + (E + 16);                   // [N+1]
    int*            cursor= off + (N + 1);                      // [N] (also cnt)

    // ---- one-time preprocessing (no s0 memcpy: layer 0 reads s0 directly)
    hipMemsetAsync(cursor, 0, sizeof(int) * N, stream);
    hist_kernel<<<1024, 256, 0, stream>>>(dst, cursor, E);
    scan_kernel<<<1, 1024, 0, stream>>>(cursor, off, N);
    hipMemcpyAsync(cursor, off, sizeof(int) * N, hipMemcpyDeviceToDevice, stream);
    scatter2_kernel<<<1024, 256, 0, stream>>>(src, dst, cursor, src_s, eid_s, E);
    conv_ea<<<2048, 256, 0, stream>>>(ea, ea_b, (long long)E * EDD / 4);
    conv_s<<<1024, 256, 0, stream>>>(s0, (unsigned int*)sb, (long long)NH / 4);
    prep_we<<<12, 256, 0, stream>>>(We, WeB);
    prep_w128<<<24, 256, 0, stream>>>(W1, W1B);
    prep_w128<<<24, 256, 0, stream>>>(W2, W2B);

    for (int l = 0; l < NLAYER; ++l) {
        const float* scur = (l == 0) ? s0 : sbuf;   // f32 state for this layer
        gine_agg_mfma<<<4096, 256, 0, stream>>>(scur, sb, src_s, eid_s, off, ea_b,
                                                WeB + (size_t)l * 16 * 64,
                                                be + l * HH, hb16, N, E);
        float* sout = (l == NLAYER - 1) ? (float*)d_out : sbuf;
        gine_mlp<<<2048, 256, 0, stream>>>(scur, hb16,
                                           W1B + (size_t)l * 32 * 64, b1 + l * HH,
                                           W2B + (size_t)l * 32 * 64, b2 + l * HH,
                                           gm + l * HH, bt + l * HH,
                                           sout, sb, N);
    }
}